// Round 17
// baseline (870.631 us; speedup 1.0000x reference)
//
#include <hip/hip_runtime.h>
#include <hip/hip_bf16.h>
#include <stdint.h>

typedef __hip_bfloat16 bf16;
typedef __attribute__((ext_vector_type(8))) short bfrag;    // 8 bf16 (4 VGPRs)
typedef __attribute__((ext_vector_type(4))) short s16x4;    // 4 bf16 (8 B)
typedef __attribute__((ext_vector_type(4))) float f32x4;

#define NPTS 8192
#define KSEL 20
#define MBIG (NPTS*KSEL)   // 163840
#define EPSN 1e-5f

__device__ __forceinline__ float lrelu(float x){ return x >= 0.f ? x : 0.2f*x; }
__device__ __forceinline__ float ldx(const void* p, int i, int isbf){
  return isbf ? __bfloat162float(((const bf16*)p)[i]) : ((const float*)p)[i];
}
__device__ __forceinline__ short f2bs(float f){
  union { bf16 h; short s; } u;
  u.h = __float2bfloat16(f);
  return u.s;
}
__device__ __forceinline__ float bs2f(short s){
  return __uint_as_float(((unsigned)(unsigned short)s) << 16);
}
__device__ __forceinline__ f32x4 mfma16(bfrag a, bfrag b, f32x4 c){
  return __builtin_amdgcn_mfma_f32_16x16x32_bf16(a, b, c, 0, 0, 0);
}
__device__ __forceinline__ unsigned fenc(float x){
  unsigned u = __float_as_uint(x);
  return (u & 0x80000000u) ? ~u : (u | 0x80000000u);
}
__device__ __forceinline__ float fdec(unsigned u){
  return __uint_as_float((u & 0x80000000u) ? (u & 0x7FFFFFFFu) : ~u);
}
__device__ __forceinline__ unsigned long long u64min(unsigned long long a, unsigned long long b){ return a<b?a:b; }
__device__ __forceinline__ unsigned long long u64max(unsigned long long a, unsigned long long b){ return a<b?b:a; }
__device__ __forceinline__ void ce(unsigned long long &a, unsigned long long &b, bool asc){
  unsigned long long mn = a<b?a:b, mx = a<b?b:a;
  a = asc ? mn : mx;
  b = asc ? mx : mn;
}

// ---------------------------------------------------------------- zero
__global__ void zero_kernel(float* __restrict__ p, int n){
  int i = blockIdx.x*256 + threadIdx.x;
  if (i < n) p[i] = 0.f;
}

// ---------------------------------------------------------------- dtype probe
__global__ void detect_kernel(const void* __restrict__ x, int* __restrict__ badf){
  int i = blockIdx.x*256 + threadIdx.x;
  int bad = 0;
  for (; i < NPTS*3; i += gridDim.x*256){
    float v = __bfloat162float(((const bf16*)x)[i]);
    if (!(fabsf(v) < 1000.0f)) bad = 1;
  }
  if (__any(bad) && (threadIdx.x & 63) == 0) atomicOr(badf, 1);
}

// ---------------------------------------------------------------- kNN (round-16: wave-per-point register sort)
__global__ __launch_bounds__(256) void knn_kernel(const void* __restrict__ x,
                                                  const int* __restrict__ tag,
                                                  int* __restrict__ idxc,
                                                  const int* __restrict__ flagp){
  __shared__ unsigned idxsh[4][1024];
  const int isbf = (*flagp == 0);
  const int t = threadIdx.x;
  const int w = t >> 6, lane = t & 63;
  const int i = blockIdx.x*4 + w;
  const int base = (i >> 10) << 10;
  const float xi = ldx(x, i*3+0, isbf);
  const float yi = ldx(x, i*3+1, isbf);
  const float zi = ldx(x, i*3+2, isbf);
  const float sqi = xi*xi + yi*yi + zi*zi;
  const int tagi = tag[i];

  const int j0 = base + 16*lane;
  float cx[16], cy[16], cz[16];
  if (isbf){
    short sbuf[48];
    const short4* ps = (const short4*)((const bf16*)x + (size_t)j0*3);
    #pragma unroll
    for (int u = 0; u < 12; u++) *(short4*)&sbuf[u*4] = ps[u];
    #pragma unroll
    for (int r = 0; r < 16; r++){
      cx[r] = bs2f(sbuf[3*r+0]);
      cy[r] = bs2f(sbuf[3*r+1]);
      cz[r] = bs2f(sbuf[3*r+2]);
    }
  } else {
    float fbuf[48];
    const float4* pf = (const float4*)((const float*)x + (size_t)j0*3);
    #pragma unroll
    for (int u = 0; u < 12; u++) *(float4*)&fbuf[u*4] = pf[u];
    #pragma unroll
    for (int r = 0; r < 16; r++){
      cx[r] = fbuf[3*r+0];
      cy[r] = fbuf[3*r+1];
      cz[r] = fbuf[3*r+2];
    }
  }
  int tgs[16];
  #pragma unroll
  for (int u = 0; u < 4; u++){
    int4 t4 = *(const int4*)(tag + j0 + u*4);
    tgs[u*4+0] = t4.x; tgs[u*4+1] = t4.y; tgs[u*4+2] = t4.z; tgs[u*4+3] = t4.w;
  }

  unsigned long long v[16];
  #pragma unroll
  for (int r = 0; r < 16; r++){
    int gj = j0 + r;
    float xj = cx[r], yj = cy[r], zj = cz[r];
    float sqj = xj*xj + yj*yj + zj*zj;
    float dot = xi*xj + yi*yj + zi*zj;
    float d2 = sqi + sqj - 2.0f*dot;
    bool valid = (gj != i) && (tgs[r] == tagi);
    unsigned k = valid ? fenc(d2) : 0xFFFFFFFFu;
    v[r] = ((unsigned long long)k << 32) | (unsigned)gj;
  }

  #pragma unroll
  for (int ksz = 2; ksz <= 1024; ksz <<= 1){
    #pragma unroll
    for (int jj = ksz >> 1; jj > 0; jj >>= 1){
      if (jj >= 16){
        const int mask = jj >> 4;
        const bool bk = ((lane & (ksz >> 4)) == 0);
        const bool keep_min = (bk == ((lane & mask) == 0));
        #pragma unroll
        for (int r = 0; r < 16; r++){
          unsigned long long o = __shfl_xor(v[r], mask, 64);
          v[r] = keep_min ? u64min(v[r], o) : u64max(v[r], o);
        }
      } else {
        const bool ascL = (ksz >= 32) ? ((lane & (ksz >> 4)) == 0)
                        : (ksz == 16) ? ((lane & 1) == 0) : true;
        #pragma unroll
        for (int r = 0; r < 16; r++){
          if ((r & jj) == 0){
            bool asc = (ksz <= 8) ? ((r & ksz) == 0) : ascL;
            ce(v[r], v[r | jj], asc);
          }
        }
      }
    }
  }

  #pragma unroll
  for (int r = 0; r < 16; r++)
    idxsh[w][(r << 6) | lane] = (unsigned)(v[r] & 0xFFFFFFFFu);
  __syncthreads();
  for (int o = lane; o < 80; o += 64){
    int s = o / 20, k = o - s*20;
    int step = (s == 0) ? 1 : (s == 1) ? 2 : (s == 2) ? 6 : 18;
    int p = k*step;
    idxc[i*80 + o] = (int)idxsh[w][((p & 15) << 6) | (p >> 4)];
  }
}

// ---------------------------------------------------------------- stage-1 P/Q (scalar, K=3)
__global__ __launch_bounds__(256) void pq3_kernel(
    const void* __restrict__ xin, const void* __restrict__ Wc,
    float* __restrict__ Pt, float* __restrict__ Qt,
    const int* __restrict__ flagp)
{
  __shared__ float WaS[16][3], WdS[16][3];
  const int isbf = (*flagp == 0);
  const int t = threadIdx.x;
  const int n0 = (blockIdx.x & 31) * 256;
  const int cg = (blockIdx.x >> 5) * 16;
  if (t < 48){
    int r = t / 3, k = t - r*3;
    float wa = ldx(Wc, (cg + r)*6 + k, isbf);
    float wb = ldx(Wc, (cg + r)*6 + 3 + k, isbf);
    WaS[r][k] = wa; WdS[r][k] = wb - wa;
  }
  __syncthreads();
  const int n = n0 + t;
  float xr[3];
  #pragma unroll
  for (int k = 0; k < 3; k++) xr[k] = ldx(xin, n*3 + k, isbf);
  float pv[16], qv[16];
  #pragma unroll
  for (int r = 0; r < 16; r++){
    float p = 0.f, q = 0.f;
    #pragma unroll
    for (int k = 0; k < 3; k++){
      p += WaS[r][k] * xr[k];
      q += WdS[r][k] * xr[k];
    }
    pv[r] = p; qv[r] = q;
  }
  #pragma unroll
  for (int r4 = 0; r4 < 4; r4++){
    *(float4*)&Pt[n*64 + cg + r4*4] = make_float4(pv[r4*4], pv[r4*4+1], pv[r4*4+2], pv[r4*4+3]);
    *(float4*)&Qt[n*64 + cg + r4*4] = make_float4(qv[r4*4], qv[r4*4+1], qv[r4*4+2], qv[r4*4+3]);
  }
}

// ---------------------------------------------------------------- P/Q via MFMA (stages 2-4)
__global__ __launch_bounds__(256) void pqm_kernel(
    const float* __restrict__ rmaxp,
    const void* __restrict__ Wc,          // [64][128] = (Wa|Wb)
    const float* __restrict__ straw,
    const float* __restrict__ resid,
    float* __restrict__ Pt, float* __restrict__ Qt,
    float* __restrict__ xout,
    const int* __restrict__ flagp)
{
  __shared__ __align__(16) short Fs[32][72];
  __shared__ float nm[64], niv[64];
  const int isbf = (*flagp == 0);
  const int t = threadIdx.x;
  const int n0 = blockIdx.x * 32;
  const int lane = t & 63, w = t >> 6;
  const int nn = lane & 15, quad = lane >> 4;

  if (t < 64){
    const float invMB = 1.0f/(float)MBIG;
    float m = straw[t] * invMB;
    float vv = straw[256+t]*invMB - m*m;
    nm[t] = m;
    niv[t] = 1.0f / sqrtf(fmaxf(vv, 0.f) + EPSN);
  }

  bfrag ap0, ap1, aq0, aq1;
  {
    const int row = 16*w + nn;
    #pragma unroll
    for (int j = 0; j < 8; j++){
      float wa0 = ldx(Wc, row*128 +      quad*8 + j, isbf);
      float wa1 = ldx(Wc, row*128 + 32 + quad*8 + j, isbf);
      float wb0 = ldx(Wc, row*128 + 64 + quad*8 + j, isbf);
      float wb1 = ldx(Wc, row*128 + 96 + quad*8 + j, isbf);
      ap0[j] = f2bs(wa0); ap1[j] = f2bs(wa1);
      aq0[j] = f2bs(wb0 - wa0); aq1[j] = f2bs(wb1 - wa1);
    }
  }
  __syncthreads();   // nm/niv ready

  {
    const int jc = t & 31, kg = t >> 5;
    const int n = n0 + jc;
    #pragma unroll
    for (int u = 0; u < 2; u++){
      s16x4 pk;
      #pragma unroll
      for (int z = 0; z < 4; z++){
        int k = kg*8 + u*4 + z;
        float rv = rmaxp[k*NPTS + n];
        float vx = lrelu((rv - nm[k]) * niv[k]) + (resid ? resid[k*NPTS + n] : 0.f);
        xout[k*NPTS + n] = vx;
        pk[z] = f2bs(vx);
      }
      *(s16x4*)&Fs[jc][kg*8 + u*4] = pk;
    }
  }
  __syncthreads();

  #pragma unroll
  for (int q = 0; q < 2; q++){
    bfrag b0 = *(bfrag*)&Fs[q*16 + nn][quad*8];
    bfrag b1 = *(bfrag*)&Fs[q*16 + nn][32 + quad*8];
    f32x4 accp = {0.f,0.f,0.f,0.f}, accq = {0.f,0.f,0.f,0.f};
    accp = mfma16(ap0, b0, accp); accp = mfma16(ap1, b1, accp);
    accq = mfma16(aq0, b0, accq); accq = mfma16(aq1, b1, accq);
    int n = n0 + q*16 + nn;
    int c0 = 16*w + quad*4;
    *(float4*)&Pt[n*64 + c0] = make_float4(accp[0], accp[1], accp[2], accp[3]);
    *(float4*)&Qt[n*64 + c0] = make_float4(accq[0], accq[1], accq[2], accq[3]);
  }
}

// ---------------------------------------------------------------- conv1 stats (16-pt)
// ET=1: additionally materialize e (bf16) to et[tile][p*20+k][chan].
template<int ET>
__global__ __launch_bounds__(256) void stats1_kernel(
    const float* __restrict__ Pt, const float* __restrict__ Qt,
    const int* __restrict__ idxc, int sidx, float* __restrict__ stats,
    short* __restrict__ et)
{
  __shared__ __align__(16) float Qs[1024];
  __shared__ int ids[320];
  const int t = threadIdx.x;
  const int n0 = blockIdx.x * 16;
  short* etb = ET ? (et + (size_t)blockIdx.x*320*64) : nullptr;
  for (int l = t; l < 1024; l += 256) Qs[l] = Qt[n0*64 + l];
  for (int l = t; l < 320; l += 256){
    int p = l / 20, k = l - p*20;
    ids[l] = idxc[(n0+p)*80 + sidx*20 + k] & (NPTS-1);
  }
  __syncthreads();
  const int tx = t & 15, ty = t >> 4;
  const int kq = tx >> 2, p0 = (tx & 3)*4;
  float sacc[4] = {0,0,0,0}, qacc[4] = {0,0,0,0};
  #pragma unroll
  for (int s = 0; s < 5; s++){
    int k = s*4 + kq;
    #pragma unroll
    for (int j = 0; j < 4; j++){
      int p = p0 + j;
      int nb = ids[p*20 + k];
      float4 pvv = *(const float4*)&Pt[nb*64 + ty*4];
      float4 qvv = *(const float4*)&Qs[p*64 + ty*4];
      float e0 = pvv.x+qvv.x, e1 = pvv.y+qvv.y, e2 = pvv.z+qvv.z, e3 = pvv.w+qvv.w;
      sacc[0]+=e0; sacc[1]+=e1; sacc[2]+=e2; sacc[3]+=e3;
      qacc[0]+=e0*e0; qacc[1]+=e1*e1; qacc[2]+=e2*e2; qacc[3]+=e3*e3;
      if (ET){
        s16x4 ev;
        ev[0] = f2bs(e0); ev[1] = f2bs(e1); ev[2] = f2bs(e2); ev[3] = f2bs(e3);
        *(s16x4*)&etb[(size_t)(p*20 + k)*64 + ty*4] = ev;
      }
    }
  }
  #pragma unroll
  for (int i = 0; i < 4; i++){
    float s = sacc[i], q = qacc[i];
    #pragma unroll
    for (int off = 8; off; off >>= 1){
      s += __shfl_down(s, off, 16);
      q += __shfl_down(q, off, 16);
    }
    if (tx == 0){
      atomicAdd(&stats[ty*4+i], s);
      atomicAdd(&stats[256+ty*4+i], q);
    }
  }
}

// ---------------------------------------------------------------- conv2 (MFMA, 16-pt, single-buffer)
// ET=0: gather e = Pt[nb]+Qs[p] (round-16 path). ET=1: read e from et (no gather).
template<int ET>
__global__ __launch_bounds__(256) void conv2_kernel(
    const float* __restrict__ Pt, const float* __restrict__ Qt,
    const int* __restrict__ idxc, int sidx,
    const void* __restrict__ W2c,
    const float* __restrict__ st1raw,
    float* __restrict__ stats2,
    float* __restrict__ rawmax,             // [64][NPTS]
    const short* __restrict__ et,
    const int* __restrict__ flagp)
{
  __shared__ __align__(16) short Gs[64][72];   // [col][chan]
  __shared__ __align__(16) float Qs[1024];
  __shared__ int ids[320];
  __shared__ float nm1[64], niv1[64];
  const int isbf = (*flagp == 0);
  const int t = threadIdx.x;
  const int n0 = blockIdx.x * 16;
  const float invMB = 1.0f/(float)MBIG;
  const short* etb = ET ? (et + (size_t)blockIdx.x*320*64) : nullptr;

  if (!ET){
    for (int l = t; l < 1024; l += 256) Qs[l] = Qt[n0*64 + l];
    for (int l = t; l < 320; l += 256){
      int p = l / 20, k = l - p*20;
      ids[l] = idxc[(n0+p)*80 + sidx*20 + k] & (NPTS-1);
    }
  }
  if (t < 64){
    float m = st1raw[t] * invMB;
    float v = st1raw[256+t]*invMB - m*m;
    nm1[t] = m;
    niv1[t] = 1.0f / sqrtf(fmaxf(v, 0.f) + EPSN);
  }

  const int lane = t & 63, w = t >> 6;
  const int nn = lane & 15, quad = lane >> 4;
  bfrag af0, af1;
  #pragma unroll
  for (int j = 0; j < 8; j++){
    af0[j] = f2bs(ldx(W2c, (16*w + nn)*64 +      quad*8 + j, isbf));
    af1[j] = f2bs(ldx(W2c, (16*w + nn)*64 + 32 + quad*8 + j, isbf));
  }
  __syncthreads();

  const int tx = t & 15, ty = t >> 4;
  float sacc[4] = {0,0,0,0}, qacc[4] = {0,0,0,0};
  float mxr[4] = {-3.4e38f,-3.4e38f,-3.4e38f,-3.4e38f};

  for (int s = 0; s < 5; s++){
    #pragma unroll
    for (int j = 0; j < 4; j++){
      int cg = tx*4 + j;
      int q = cg >> 4, p = cg & 15;
      float e[4];
      if (ET){
        s16x4 ev = *(const s16x4*)&etb[(size_t)(p*20 + s*4 + q)*64 + ty*4];
        e[0] = bs2f(ev[0]); e[1] = bs2f(ev[1]);
        e[2] = bs2f(ev[2]); e[3] = bs2f(ev[3]);
      } else {
        int nb = ids[p*20 + s*4 + q];
        float4 pvv = *(const float4*)&Pt[nb*64 + ty*4];
        float4 qvv = *(const float4*)&Qs[p*64 + ty*4];
        e[0] = pvv.x+qvv.x; e[1] = pvv.y+qvv.y;
        e[2] = pvv.z+qvv.z; e[3] = pvv.w+qvv.w;
      }
      s16x4 gv;
      #pragma unroll
      for (int i = 0; i < 4; i++)
        gv[i] = f2bs(lrelu((e[i] - nm1[ty*4+i]) * niv1[ty*4+i]));
      *(s16x4*)&Gs[cg][ty*4] = gv;
    }
    __syncthreads();
    #pragma unroll
    for (int q = 0; q < 4; q++){
      bfrag b0 = *(bfrag*)&Gs[q*16 + nn][quad*8];
      bfrag b1 = *(bfrag*)&Gs[q*16 + nn][32 + quad*8];
      f32x4 acc = {0.f, 0.f, 0.f, 0.f};
      acc = mfma16(af0, b0, acc);
      acc = mfma16(af1, b1, acc);
      #pragma unroll
      for (int r = 0; r < 4; r++){
        float v = acc[r];
        sacc[r] += v; qacc[r] += v*v;
        mxr[r] = fmaxf(mxr[r], v);
      }
    }
    __syncthreads();
  }

  #pragma unroll
  for (int r = 0; r < 4; r++){
    int rr = 16*w + quad*4 + r;
    float s = sacc[r], q2 = qacc[r];
    #pragma unroll
    for (int off = 8; off; off >>= 1){
      s  += __shfl_down(s, off, 16);
      q2 += __shfl_down(q2, off, 16);
    }
    if (nn == 0){
      atomicAdd(&stats2[rr], s);
      atomicAdd(&stats2[256+rr], q2);
    }
    rawmax[rr*NPTS + n0 + nn] = mxr[r];
  }
}

// ---------------------------------------------------------------- W9 GEMM (K=256) with fused maxres->x4
__global__ __launch_bounds__(256) void gemm9_kernel(
    const void* __restrict__ W,
    const float* __restrict__ xs,
    const float* __restrict__ rmaxp, const float* __restrict__ st2raw,
    const float* __restrict__ x3, float* __restrict__ x4,
    float* __restrict__ stats, unsigned* __restrict__ maxenc,
    const int* __restrict__ flagp)
{
  __shared__ __align__(16) short Fs[64][72];
  __shared__ float nm2[64], niv2[64];
  const int t = threadIdx.x;
  const int isbf = (*flagp == 0);
  const int colbase = (blockIdx.x & 127) * 64;
  const int rb = (blockIdx.x >> 7) * 64;
  const int lane = t & 63, w = t >> 6;
  const int nn = lane & 15, quad = lane >> 4;

  if (t < 64){
    const float invMB = 1.0f/(float)MBIG;
    float m = st2raw[t] * invMB;
    float v = st2raw[256+t]*invMB - m*m;
    nm2[t] = m;
    niv2[t] = 1.0f / sqrtf(fmaxf(v, 0.f) + EPSN);
  }

  bfrag af[8];
  const int arow = rb + 16*w + nn;
  #pragma unroll
  for (int f = 0; f < 8; f++)
    #pragma unroll
    for (int j = 0; j < 8; j++)
      af[f][j] = f2bs(ldx(W, arow*256 + f*32 + quad*8 + j, isbf));

  f32x4 acc[4] = {};
  const int jcol = t & 63, kg = t >> 6;

  for (int kc = 0; kc < 256; kc += 64){
    __syncthreads();
    #pragma unroll
    for (int u = 0; u < 4; u++){
      int kl = kg*16 + u*4;
      s16x4 pk;
      #pragma unroll
      for (int z = 0; z < 4; z++){
        int k = kc + kl + z;
        float v;
        if (k < 192){
          v = xs[k*NPTS + colbase + jcol];
        } else {
          int kk = k - 192;
          float rv = rmaxp[kk*NPTS + colbase + jcol];
          v = lrelu((rv - nm2[kk]) * niv2[kk]) + x3[kk*NPTS + colbase + jcol];
          if (rb == 0) x4[kk*NPTS + colbase + jcol] = v;
        }
        pk[z] = f2bs(v);
      }
      *(s16x4*)&Fs[jcol][kl] = pk;
    }
    __syncthreads();
    const int f0 = kc >> 5;
    #pragma unroll
    for (int q = 0; q < 4; q++){
      bfrag b0 = *(bfrag*)&Fs[q*16+nn][quad*8];
      bfrag b1 = *(bfrag*)&Fs[q*16+nn][32 + quad*8];
      acc[q] = mfma16(af[f0],   b0, acc[q]);
      acc[q] = mfma16(af[f0+1], b1, acc[q]);
    }
  }

  #pragma unroll
  for (int r = 0; r < 4; r++){
    int rr = rb + 16*w + quad*4 + r;
    float sum = 0.f, q2 = 0.f, mxv = -3.4e38f;
    #pragma unroll
    for (int q = 0; q < 4; q++){
      float v = acc[q][r];
      sum += v; q2 += v*v; mxv = fmaxf(mxv, v);
    }
    #pragma unroll
    for (int off = 8; off; off >>= 1){
      sum += __shfl_down(sum, off, 16);
      q2  += __shfl_down(q2, off, 16);
      mxv  = fmaxf(mxv, __shfl_down(mxv, off, 16));
    }
    if (nn == 0){
      atomicAdd(&stats[rr], sum);
      atomicAdd(&stats[256+rr], q2);
      atomicMax(&maxenc[rr], fenc(mxv));
    }
  }
}

// ---------------------------------------------------------------- W10 GEMM (K=64) with fused finalize_g
__global__ __launch_bounds__(256) void gemm10_kernel(
    const void* __restrict__ W,
    const float* __restrict__ B,            // x4
    const float* __restrict__ statsG, const unsigned* __restrict__ gmaxenc,
    float* __restrict__ Y,
    float* __restrict__ stats,
    const int* __restrict__ flagp)
{
  __shared__ __align__(16) short Fs[64][72];
  __shared__ float gsh[128], c0s[64];
  const int t = threadIdx.x;
  const int isbf = (*flagp == 0);
  const int colbase = (blockIdx.x & 127) * 64;
  const int rb = (blockIdx.x >> 7) * 64;
  const int lane = t & 63, w = t >> 6;
  const int nn = lane & 15, quad = lane >> 4;
  const float invMN = 1.0f/(float)NPTS;

  if (t < 128){
    float m = statsG[t] * invMN;
    float v = statsG[256+t]*invMN - m*m;
    float iv = 1.0f / sqrtf(fmaxf(v, 0.f) + EPSN);
    gsh[t] = lrelu((fdec(gmaxenc[t]) - m) * iv);
  }
  __syncthreads();
  if (t < 64){
    float s = 0.f;
    for (int j = 0; j < 128; j++) s += ldx(W, (rb + t)*192 + j, isbf) * gsh[j];
    c0s[t] = s;
  }

  bfrag af[2];
  const int arow = rb + 16*w + nn;
  #pragma unroll
  for (int f = 0; f < 2; f++)
    #pragma unroll
    for (int j = 0; j < 8; j++)
      af[f][j] = f2bs(ldx(W, arow*192 + 128 + f*32 + quad*8 + j, isbf));

  f32x4 acc[4] = {};
  const int jcol = t & 63, kg = t >> 6;

  {
    __syncthreads();
    #pragma unroll
    for (int u = 0; u < 4; u++){
      int kl = kg*16 + u*4;
      s16x4 pk;
      #pragma unroll
      for (int z = 0; z < 4; z++){
        int k = kl + z;
        pk[z] = f2bs(B[k*NPTS + colbase + jcol]);
      }
      *(s16x4*)&Fs[jcol][kl] = pk;
    }
    __syncthreads();
    #pragma unroll
    for (int q = 0; q < 4; q++){
      bfrag b0 = *(bfrag*)&Fs[q*16+nn][quad*8];
      bfrag b1 = *(bfrag*)&Fs[q*16+nn][32 + quad*8];
      acc[q] = mfma16(af[0], b0, acc[q]);
      acc[q] = mfma16(af[1], b1, acc[q]);
    }
  }

  #pragma unroll
  for (int r = 0; r < 4; r++){
    int rl = 16*w + quad*4 + r;
    int rr = rb + rl;
    float cv = c0s[rl];
    float sum = 0.f, q2 = 0.f;
    #pragma unroll
    for (int q = 0; q < 4; q++){
      float v = acc[q][r] + cv;
      sum += v; q2 += v*v;
      Y[rr*NPTS + colbase + q*16 + nn] = v;
    }
    #pragma unroll
    for (int off = 8; off; off >>= 1){
      sum += __shfl_down(sum, off, 16);
      q2  += __shfl_down(q2, off, 16);
    }
    if (nn == 0){
      atomicAdd(&stats[rr], sum);
      atomicAdd(&stats[256+rr], q2);
    }
  }
}

// ---------------------------------------------------------------- 1d GEMMs (MFMA)
template<int CTOT>
__global__ __launch_bounds__(256) void gemm1d_kernel(
    const void* __restrict__ W, int ldw, int koffW,
    const float* __restrict__ A, const float* __restrict__ Araw, float invA, int CA,
    const float* __restrict__ B,
    const float* __restrict__ cvec,
    float* __restrict__ Y,
    float* __restrict__ stats, unsigned* __restrict__ maxenc,
    const int* __restrict__ flagp)
{
  __shared__ __align__(16) short Fs[64][72];
  __shared__ float am[256], aiv[256];
  const int t = threadIdx.x;
  const int isbf = (*flagp == 0);
  const int colbase = (blockIdx.x & 127) * 64;
  const int rb = (blockIdx.x >> 7) * 64;
  const int lane = t & 63, w = t >> 6;
  const int nn = lane & 15, quad = lane >> 4;

  if (Araw && t < CA){
    float m = Araw[t]*invA;
    float v = Araw[256+t]*invA - m*m;
    am[t] = m; aiv[t] = 1.0f/sqrtf(fmaxf(v,0.f)+EPSN);
  }

  constexpr int K32 = CTOT >> 5;
  bfrag af[K32];
  const int arow = rb + 16*w + nn;
  #pragma unroll
  for (int f = 0; f < K32; f++)
    #pragma unroll
    for (int j = 0; j < 8; j++)
      af[f][j] = f2bs(ldx(W, arow*ldw + koffW + f*32 + quad*8 + j, isbf));

  f32x4 acc[4] = {};
  const int jcol = t & 63, kg = t >> 6;

  for (int kc = 0; kc < CTOT; kc += 64){
    __syncthreads();
    #pragma unroll
    for (int u = 0; u < 4; u++){
      int kl = kg*16 + u*4;
      s16x4 pk;
      #pragma unroll
      for (int z = 0; z < 4; z++){
        int k = kc + kl + z;
        float v;
        if (k < CA){
          v = A[k*NPTS + colbase + jcol];
          if (Araw) v = lrelu((v - am[k]) * aiv[k]);
        } else {
          v = B[(k-CA)*NPTS + colbase + jcol];
        }
        pk[z] = f2bs(v);
      }
      *(s16x4*)&Fs[jcol][kl] = pk;
    }
    __syncthreads();
    const int f0 = kc >> 5;
    #pragma unroll
    for (int q = 0; q < 4; q++){
      bfrag b0 = *(bfrag*)&Fs[q*16+nn][quad*8];
      bfrag b1 = *(bfrag*)&Fs[q*16+nn][32 + quad*8];
      acc[q] = mfma16(af[f0],   b0, acc[q]);
      acc[q] = mfma16(af[f0+1], b1, acc[q]);
    }
  }

  #pragma unroll
  for (int r = 0; r < 4; r++){
    int rr = rb + 16*w + quad*4 + r;
    float cv = cvec ? cvec[rr] : 0.f;
    float sum = 0.f, q2 = 0.f, mxv = -3.4e38f;
    #pragma unroll
    for (int q = 0; q < 4; q++){
      float v = acc[q][r] + cv;
      sum += v; q2 += v*v; mxv = fmaxf(mxv, v);
      if (Y) Y[rr*NPTS + colbase + q*16 + nn] = v;
    }
    #pragma unroll
    for (int off = 8; off; off >>= 1){
      sum += __shfl_down(sum, off, 16);
      q2  += __shfl_down(q2, off, 16);
      mxv  = fmaxf(mxv, __shfl_down(mxv, off, 16));
    }
    if (nn == 0){
      atomicAdd(&stats[rr], sum);
      atomicAdd(&stats[256+rr], q2);
      if (maxenc) atomicMax(&maxenc[rr], fenc(mxv));
    }
  }
}

// ---------------------------------------------------------------- segment sum
__global__ __launch_bounds__(256) void segsum_kernel(
    const float* __restrict__ ybuf, const float* __restrict__ straw,
    const int* __restrict__ tag, float* __restrict__ seg, float* __restrict__ cnt)
{
  const float invMN = 1.0f/(float)NPTS;
  int g = blockIdx.x*256 + threadIdx.x;
  int c = g >> 13, n = g & (NPTS-1);
  float m = straw[c] * invMN;
  float vv = straw[256+c]*invMN - m*m;
  float iv = 1.0f / sqrtf(fmaxf(vv, 0.f) + EPSN);
  float v = lrelu((ybuf[c*NPTS + n] - m) * iv);
  int tg = tag[n] & 7;
  int lane = threadIdx.x & 63;
  int t0 = __shfl(tg, 0, 64);
  bool uni = __all(tg == t0);
  if (uni){
    #pragma unroll
    for (int off = 32; off; off >>= 1) v += __shfl_down(v, off, 64);
    if (lane == 0){
      atomicAdd(&seg[t0*64 + c], v);
      if (c == 0) atomicAdd(cnt + t0, 64.f);
    }
  } else {
    atomicAdd(&seg[tg*64 + c], v);
    if (c == 0) atomicAdd(cnt + tg, 1.f);
  }
}

// ---------------------------------------------------------------- final out
__global__ void final_kernel(const void* __restrict__ Wr,
    const float* __restrict__ seg, const float* __restrict__ cnt,
    void* __restrict__ out, int total, const int* __restrict__ flagp)
{
  const int isbf = (*flagp == 0);
  int q = blockIdx.x*blockDim.x + threadIdx.x;
  if (q >= total) return;
  int g = q >> 7, c = q & 127;
  float s = 0.f;
  for (int j = 0; j < 64; j++) s += ldx(Wr, c*64 + j, isbf) * seg[g*64 + j];
  float r = s / fmaxf(cnt[g], 1.f);
  if (isbf) ((bf16*)out)[q] = __float2bfloat16(r);
  else      ((float*)out)[q] = r;
}

// ================================================================ host
extern "C" void kernel_launch(void* const* d_in, const int* in_sizes, int n_in,
                              void* d_out, int out_size, void* d_ws, size_t ws_size,
                              hipStream_t stream)
{
  const void* x   = d_in[0];
  const int* tag  = (const int*)d_in[1];
  const void* W1  = d_in[3];
  const void* W2  = d_in[4];
  const void* W3  = d_in[5];
  const void* W4  = d_in[6];
  const void* W5  = d_in[7];
  const void* W6  = d_in[8];
  const void* W7  = d_in[9];
  const void* W8  = d_in[10];
  const void* W9  = d_in[11];
  const void* W10 = d_in[12];
  const void* W11 = d_in[13];
  const void* W12 = d_in[14];
  const void* W13 = d_in[15];
  const void* Wr  = d_in[16];

  char* ws = (char*)d_ws;
  int*      idxc = (int*)ws;                        // 8192*80*4   = 2,621,440
  float*    xs   = (float*)(ws + 2621440);          // 4*64*8192*4 = 8,388,608
  float* x1 = xs;
  float* x2 = xs +  64*NPTS;
  float* x3 = xs + 128*NPTS;
  float* x4 = xs + 192*NPTS;
  float*    y0   = (float*)(ws + 11010048);         // 128*8192*4 = 4,194,304
  float*    y1   = (float*)(ws + 15204352);         // 4,194,304
  float*    rmax = (float*)(ws + 19398656);         // 64*8192*4  = 2,097,152
  float*    Pt   = y0;                              // alias: P/Q dead before decoder
  float*    Qt   = y0 + 64*NPTS;
  float*    st   = (float*)(ws + 21495808);         // 16384 floats (64 KB)
  short*    et   = (short*)(ws + 21561344);         // e scratch, 20,971,520 B
  auto L = [&](int l){ return st + l*1024; };       // raw sum|sumsq x256 each
  int*      flag     = (int*)(st + 13312);          // badf: 0 => bf16
  unsigned* gmaxenc  = (unsigned*)(st + 13440);
  float*    seg      = st + 13824;
  float*    cnt      = seg + 512;

  const bool bigws = ws_size >= (size_t)(21561344 + 20971520);

  zero_kernel<<<64, 256, 0, stream>>>(st, 16384);
  detect_kernel<<<12, 256, 0, stream>>>(x, flag);
  knn_kernel<<<2048, 256, 0, stream>>>(x, tag, idxc, flag);

#define STAGE(SIDX, WB, LA, LB)                                                              \
  if (bigws){                                                                                \
    stats1_kernel<1><<<512, 256, 0, stream>>>(Pt, Qt, idxc, SIDX, LA, et);                   \
    conv2_kernel<1><<<512, 256, 0, stream>>>(Pt, Qt, idxc, SIDX, WB, LA, LB, rmax, et, flag);\
  } else {                                                                                   \
    stats1_kernel<0><<<512, 256, 0, stream>>>(Pt, Qt, idxc, SIDX, LA, nullptr);              \
    conv2_kernel<0><<<512, 256, 0, stream>>>(Pt, Qt, idxc, SIDX, WB, LA, LB, rmax,           \
                                             nullptr, flag);                                 \
  }

  // stage 1
  pq3_kernel<<<128, 256, 0, stream>>>(x, W1, Pt, Qt, flag);
  STAGE(0, W2, L(0), L(1))
  // stage 2 (pqm fuses maxres of stage 1 -> x1)
  pqm_kernel<<<256, 256, 0, stream>>>(rmax, W3, L(1), nullptr, Pt, Qt, x1, flag);
  STAGE(1, W4, L(2), L(3))
  // stage 3 (fused maxres of stage 2 -> x2, resid x1)
  pqm_kernel<<<256, 256, 0, stream>>>(rmax, W5, L(3), x1, Pt, Qt, x2, flag);
  STAGE(2, W6, L(4), L(5))
  // stage 4 (fused maxres of stage 3 -> x3, resid x2)
  pqm_kernel<<<256, 256, 0, stream>>>(rmax, W7, L(5), x2, Pt, Qt, x3, flag);
  STAGE(3, W8, L(6), L(7))
#undef STAGE

  // ---- g: W9 GEMM with fused maxres (x4 materialized as byproduct)
  gemm9_kernel<<<256, 256, 0, stream>>>(W9, xs, rmax, L(7), x3, x4,
                                        L(8), gmaxenc, flag);

  const float invMN = 1.0f/(float)NPTS;
  // ---- decoder chain (W10 fuses finalize_g)
  gemm10_kernel<<<256, 256, 0, stream>>>(W10, x4, L(8), gmaxenc, y0, L(9), flag);
  gemm1d_kernel<192><<<256, 256, 0, stream>>>(W11, 192, 0, y0, L(9), invMN, 128,
                                              x3, nullptr, y1, L(10), nullptr, flag);
  gemm1d_kernel<192><<<128, 256, 0, stream>>>(W12, 192, 0, y1, L(10), invMN, 128,
                                              x2, nullptr, y0, L(11), nullptr, flag);
  gemm1d_kernel<128><<<128, 256, 0, stream>>>(W13, 128, 0, y0, L(11), invMN, 64,
                                              x1, nullptr, y1, L(12), nullptr, flag);

  // ---- code pooling: segment-sum commutes with Wr
  segsum_kernel<<<64*NPTS/256, 256, 0, stream>>>(y1, L(12), tag, seg, cnt);
  final_kernel<<<4, 256, 0, stream>>>(Wr, seg, cnt, d_out, out_size, flag);
}

// Round 18
// 851.562 us; speedup vs baseline: 1.0224x; 1.0224x over previous
//
#include <hip/hip_runtime.h>
#include <hip/hip_bf16.h>
#include <stdint.h>

typedef __hip_bfloat16 bf16;
typedef __attribute__((ext_vector_type(8))) short bfrag;    // 8 bf16 (4 VGPRs)
typedef __attribute__((ext_vector_type(4))) short s16x4;    // 4 bf16 (8 B)
typedef __attribute__((ext_vector_type(4))) float f32x4;

#define NPTS 8192
#define KSEL 20
#define MBIG (NPTS*KSEL)   // 163840
#define EPSN 1e-5f

__device__ __forceinline__ float lrelu(float x){ return x >= 0.f ? x : 0.2f*x; }
__device__ __forceinline__ float ldx(const void* p, int i, int isbf){
  return isbf ? __bfloat162float(((const bf16*)p)[i]) : ((const float*)p)[i];
}
__device__ __forceinline__ short f2bs(float f){
  union { bf16 h; short s; } u;
  u.h = __float2bfloat16(f);
  return u.s;
}
__device__ __forceinline__ float bs2f(short s){
  return __uint_as_float(((unsigned)(unsigned short)s) << 16);
}
__device__ __forceinline__ f32x4 mfma16(bfrag a, bfrag b, f32x4 c){
  return __builtin_amdgcn_mfma_f32_16x16x32_bf16(a, b, c, 0, 0, 0);
}
__device__ __forceinline__ unsigned fenc(float x){
  unsigned u = __float_as_uint(x);
  return (u & 0x80000000u) ? ~u : (u | 0x80000000u);
}
__device__ __forceinline__ float fdec(unsigned u){
  return __uint_as_float((u & 0x80000000u) ? (u & 0x7FFFFFFFu) : ~u);
}
__device__ __forceinline__ unsigned long long u64min(unsigned long long a, unsigned long long b){ return a<b?a:b; }
__device__ __forceinline__ unsigned long long u64max(unsigned long long a, unsigned long long b){ return a<b?b:a; }
__device__ __forceinline__ void ce(unsigned long long &a, unsigned long long &b, bool asc){
  unsigned long long mn = a<b?a:b, mx = a<b?b:a;
  a = asc ? mn : mx;
  b = asc ? mx : mn;
}

// ---------------------------------------------------------------- zero
__global__ void zero_kernel(float* __restrict__ p, int n){
  int i = blockIdx.x*256 + threadIdx.x;
  if (i < n) p[i] = 0.f;
}

// ---------------------------------------------------------------- dtype probe
__global__ void detect_kernel(const void* __restrict__ x, int* __restrict__ badf){
  int i = blockIdx.x*256 + threadIdx.x;
  int bad = 0;
  for (; i < NPTS*3; i += gridDim.x*256){
    float v = __bfloat162float(((const bf16*)x)[i]);
    if (!(fabsf(v) < 1000.0f)) bad = 1;
  }
  if (__any(bad) && (threadIdx.x & 63) == 0) atomicOr(badf, 1);
}

// ---------------------------------------------------------------- kNN (wave-per-point register sort)
__global__ __launch_bounds__(256) void knn_kernel(const void* __restrict__ x,
                                                  const int* __restrict__ tag,
                                                  int* __restrict__ idxc,
                                                  const int* __restrict__ flagp){
  __shared__ unsigned idxsh[4][1024];
  const int isbf = (*flagp == 0);
  const int t = threadIdx.x;
  const int w = t >> 6, lane = t & 63;
  const int i = blockIdx.x*4 + w;
  const int base = (i >> 10) << 10;
  const float xi = ldx(x, i*3+0, isbf);
  const float yi = ldx(x, i*3+1, isbf);
  const float zi = ldx(x, i*3+2, isbf);
  const float sqi = xi*xi + yi*yi + zi*zi;
  const int tagi = tag[i];

  const int j0 = base + 16*lane;
  float cx[16], cy[16], cz[16];
  if (isbf){
    short sbuf[48];
    const short4* ps = (const short4*)((const bf16*)x + (size_t)j0*3);
    #pragma unroll
    for (int u = 0; u < 12; u++) *(short4*)&sbuf[u*4] = ps[u];
    #pragma unroll
    for (int r = 0; r < 16; r++){
      cx[r] = bs2f(sbuf[3*r+0]);
      cy[r] = bs2f(sbuf[3*r+1]);
      cz[r] = bs2f(sbuf[3*r+2]);
    }
  } else {
    float fbuf[48];
    const float4* pf = (const float4*)((const float*)x + (size_t)j0*3);
    #pragma unroll
    for (int u = 0; u < 12; u++) *(float4*)&fbuf[u*4] = pf[u];
    #pragma unroll
    for (int r = 0; r < 16; r++){
      cx[r] = fbuf[3*r+0];
      cy[r] = fbuf[3*r+1];
      cz[r] = fbuf[3*r+2];
    }
  }
  int tgs[16];
  #pragma unroll
  for (int u = 0; u < 4; u++){
    int4 t4 = *(const int4*)(tag + j0 + u*4);
    tgs[u*4+0] = t4.x; tgs[u*4+1] = t4.y; tgs[u*4+2] = t4.z; tgs[u*4+3] = t4.w;
  }

  unsigned long long v[16];
  #pragma unroll
  for (int r = 0; r < 16; r++){
    int gj = j0 + r;
    float xj = cx[r], yj = cy[r], zj = cz[r];
    float sqj = xj*xj + yj*yj + zj*zj;
    float dot = xi*xj + yi*yj + zi*zj;
    float d2 = sqi + sqj - 2.0f*dot;
    bool valid = (gj != i) && (tgs[r] == tagi);
    unsigned k = valid ? fenc(d2) : 0xFFFFFFFFu;
    v[r] = ((unsigned long long)k << 32) | (unsigned)gj;
  }

  #pragma unroll
  for (int ksz = 2; ksz <= 1024; ksz <<= 1){
    #pragma unroll
    for (int jj = ksz >> 1; jj > 0; jj >>= 1){
      if (jj >= 16){
        const int mask = jj >> 4;
        const bool bk = ((lane & (ksz >> 4)) == 0);
        const bool keep_min = (bk == ((lane & mask) == 0));
        #pragma unroll
        for (int r = 0; r < 16; r++){
          unsigned long long o = __shfl_xor(v[r], mask, 64);
          v[r] = keep_min ? u64min(v[r], o) : u64max(v[r], o);
        }
      } else {
        const bool ascL = (ksz >= 32) ? ((lane & (ksz >> 4)) == 0)
                        : (ksz == 16) ? ((lane & 1) == 0) : true;
        #pragma unroll
        for (int r = 0; r < 16; r++){
          if ((r & jj) == 0){
            bool asc = (ksz <= 8) ? ((r & ksz) == 0) : ascL;
            ce(v[r], v[r | jj], asc);
          }
        }
      }
    }
  }

  #pragma unroll
  for (int r = 0; r < 16; r++)
    idxsh[w][(r << 6) | lane] = (unsigned)(v[r] & 0xFFFFFFFFu);
  __syncthreads();
  for (int o = lane; o < 80; o += 64){
    int s = o / 20, k = o - s*20;
    int step = (s == 0) ? 1 : (s == 1) ? 2 : (s == 2) ? 6 : 18;
    int p = k*step;
    idxc[i*80 + o] = (int)idxsh[w][((p & 15) << 6) | (p >> 4)];
  }
}

// ---------------------------------------------------------------- stage-1 P/Q (scalar, K=3)
__global__ __launch_bounds__(256) void pq3_kernel(
    const void* __restrict__ xin, const void* __restrict__ Wc,
    float* __restrict__ Pt, float* __restrict__ Qt,
    const int* __restrict__ flagp)
{
  __shared__ float WaS[16][3], WdS[16][3];
  const int isbf = (*flagp == 0);
  const int t = threadIdx.x;
  const int n0 = (blockIdx.x & 31) * 256;
  const int cg = (blockIdx.x >> 5) * 16;
  if (t < 48){
    int r = t / 3, k = t - r*3;
    float wa = ldx(Wc, (cg + r)*6 + k, isbf);
    float wb = ldx(Wc, (cg + r)*6 + 3 + k, isbf);
    WaS[r][k] = wa; WdS[r][k] = wb - wa;
  }
  __syncthreads();
  const int n = n0 + t;
  float xr[3];
  #pragma unroll
  for (int k = 0; k < 3; k++) xr[k] = ldx(xin, n*3 + k, isbf);
  float pv[16], qv[16];
  #pragma unroll
  for (int r = 0; r < 16; r++){
    float p = 0.f, q = 0.f;
    #pragma unroll
    for (int k = 0; k < 3; k++){
      p += WaS[r][k] * xr[k];
      q += WdS[r][k] * xr[k];
    }
    pv[r] = p; qv[r] = q;
  }
  #pragma unroll
  for (int r4 = 0; r4 < 4; r4++){
    *(float4*)&Pt[n*64 + cg + r4*4] = make_float4(pv[r4*4], pv[r4*4+1], pv[r4*4+2], pv[r4*4+3]);
    *(float4*)&Qt[n*64 + cg + r4*4] = make_float4(qv[r4*4], qv[r4*4+1], qv[r4*4+2], qv[r4*4+3]);
  }
}

// ---------------------------------------------------------------- P/Q via MFMA (stages 2-4)
__global__ __launch_bounds__(256) void pqm_kernel(
    const float* __restrict__ rmaxp,
    const void* __restrict__ Wc,          // [64][128] = (Wa|Wb)
    const float* __restrict__ straw,
    const float* __restrict__ resid,
    float* __restrict__ Pt, float* __restrict__ Qt,
    float* __restrict__ xout,
    const int* __restrict__ flagp)
{
  __shared__ __align__(16) short Fs[32][72];
  __shared__ float nm[64], niv[64];
  const int isbf = (*flagp == 0);
  const int t = threadIdx.x;
  const int n0 = blockIdx.x * 32;
  const int lane = t & 63, w = t >> 6;
  const int nn = lane & 15, quad = lane >> 4;

  if (t < 64){
    const float invMB = 1.0f/(float)MBIG;
    float m = straw[t] * invMB;
    float vv = straw[256+t]*invMB - m*m;
    nm[t] = m;
    niv[t] = 1.0f / sqrtf(fmaxf(vv, 0.f) + EPSN);
  }

  bfrag ap0, ap1, aq0, aq1;
  {
    const int row = 16*w + nn;
    #pragma unroll
    for (int j = 0; j < 8; j++){
      float wa0 = ldx(Wc, row*128 +      quad*8 + j, isbf);
      float wa1 = ldx(Wc, row*128 + 32 + quad*8 + j, isbf);
      float wb0 = ldx(Wc, row*128 + 64 + quad*8 + j, isbf);
      float wb1 = ldx(Wc, row*128 + 96 + quad*8 + j, isbf);
      ap0[j] = f2bs(wa0); ap1[j] = f2bs(wa1);
      aq0[j] = f2bs(wb0 - wa0); aq1[j] = f2bs(wb1 - wa1);
    }
  }
  __syncthreads();   // nm/niv ready

  {
    const int jc = t & 31, kg = t >> 5;
    const int n = n0 + jc;
    #pragma unroll
    for (int u = 0; u < 2; u++){
      s16x4 pk;
      #pragma unroll
      for (int z = 0; z < 4; z++){
        int k = kg*8 + u*4 + z;
        float rv = rmaxp[k*NPTS + n];
        float vx = lrelu((rv - nm[k]) * niv[k]) + (resid ? resid[k*NPTS + n] : 0.f);
        xout[k*NPTS + n] = vx;
        pk[z] = f2bs(vx);
      }
      *(s16x4*)&Fs[jc][kg*8 + u*4] = pk;
    }
  }
  __syncthreads();

  #pragma unroll
  for (int q = 0; q < 2; q++){
    bfrag b0 = *(bfrag*)&Fs[q*16 + nn][quad*8];
    bfrag b1 = *(bfrag*)&Fs[q*16 + nn][32 + quad*8];
    f32x4 accp = {0.f,0.f,0.f,0.f}, accq = {0.f,0.f,0.f,0.f};
    accp = mfma16(ap0, b0, accp); accp = mfma16(ap1, b1, accp);
    accq = mfma16(aq0, b0, accq); accq = mfma16(aq1, b1, accq);
    int n = n0 + q*16 + nn;
    int c0 = 16*w + quad*4;
    *(float4*)&Pt[n*64 + c0] = make_float4(accp[0], accp[1], accp[2], accp[3]);
    *(float4*)&Qt[n*64 + c0] = make_float4(accq[0], accq[1], accq[2], accq[3]);
  }
}

// ---------------------------------------------------------------- conv1 stats (16-pt)
__global__ __launch_bounds__(256) void stats1_kernel(
    const float* __restrict__ Pt, const float* __restrict__ Qt,
    const int* __restrict__ idxc, int sidx, float* __restrict__ stats)
{
  __shared__ __align__(16) float Qs[1024];
  __shared__ int ids[320];
  const int t = threadIdx.x;
  const int n0 = blockIdx.x * 16;
  for (int l = t; l < 1024; l += 256) Qs[l] = Qt[n0*64 + l];
  for (int l = t; l < 320; l += 256){
    int p = l / 20, k = l - p*20;
    ids[l] = idxc[(n0+p)*80 + sidx*20 + k] & (NPTS-1);
  }
  __syncthreads();
  const int tx = t & 15, ty = t >> 4;
  const int kq = tx >> 2, p0 = (tx & 3)*4;
  float sacc[4] = {0,0,0,0}, qacc[4] = {0,0,0,0};
  #pragma unroll
  for (int s = 0; s < 5; s++){
    int k = s*4 + kq;
    #pragma unroll
    for (int j = 0; j < 4; j++){
      int p = p0 + j;
      int nb = ids[p*20 + k];
      float4 pvv = *(const float4*)&Pt[nb*64 + ty*4];
      float4 qvv = *(const float4*)&Qs[p*64 + ty*4];
      float e0 = pvv.x+qvv.x, e1 = pvv.y+qvv.y, e2 = pvv.z+qvv.z, e3 = pvv.w+qvv.w;
      sacc[0]+=e0; sacc[1]+=e1; sacc[2]+=e2; sacc[3]+=e3;
      qacc[0]+=e0*e0; qacc[1]+=e1*e1; qacc[2]+=e2*e2; qacc[3]+=e3*e3;
    }
  }
  #pragma unroll
  for (int i = 0; i < 4; i++){
    float s = sacc[i], q = qacc[i];
    #pragma unroll
    for (int off = 8; off; off >>= 1){
      s += __shfl_down(s, off, 16);
      q += __shfl_down(q, off, 16);
    }
    if (tx == 0){
      atomicAdd(&stats[ty*4+i], s);
      atomicAdd(&stats[256+ty*4+i], q);
    }
  }
}

// ---------------------------------------------------------------- conv2 (MFMA, 16-pt, single-buffer)
__global__ __launch_bounds__(256) void conv2_kernel(
    const float* __restrict__ Pt, const float* __restrict__ Qt,
    const int* __restrict__ idxc, int sidx,
    const void* __restrict__ W2c,
    const float* __restrict__ st1raw,
    float* __restrict__ stats2,
    float* __restrict__ rawmax,             // [64][NPTS]
    const int* __restrict__ flagp)
{
  __shared__ __align__(16) short Gs[64][72];   // [col][chan]
  __shared__ __align__(16) float Qs[1024];
  __shared__ int ids[320];
  __shared__ float nm1[64], niv1[64];
  const int isbf = (*flagp == 0);
  const int t = threadIdx.x;
  const int n0 = blockIdx.x * 16;
  const float invMB = 1.0f/(float)MBIG;

  for (int l = t; l < 1024; l += 256) Qs[l] = Qt[n0*64 + l];
  for (int l = t; l < 320; l += 256){
    int p = l / 20, k = l - p*20;
    ids[l] = idxc[(n0+p)*80 + sidx*20 + k] & (NPTS-1);
  }
  if (t < 64){
    float m = st1raw[t] * invMB;
    float v = st1raw[256+t]*invMB - m*m;
    nm1[t] = m;
    niv1[t] = 1.0f / sqrtf(fmaxf(v, 0.f) + EPSN);
  }

  const int lane = t & 63, w = t >> 6;
  const int nn = lane & 15, quad = lane >> 4;
  bfrag af0, af1;
  #pragma unroll
  for (int j = 0; j < 8; j++){
    af0[j] = f2bs(ldx(W2c, (16*w + nn)*64 +      quad*8 + j, isbf));
    af1[j] = f2bs(ldx(W2c, (16*w + nn)*64 + 32 + quad*8 + j, isbf));
  }
  __syncthreads();

  const int tx = t & 15, ty = t >> 4;
  float sacc[4] = {0,0,0,0}, qacc[4] = {0,0,0,0};
  float mxr[4] = {-3.4e38f,-3.4e38f,-3.4e38f,-3.4e38f};

  for (int s = 0; s < 5; s++){
    #pragma unroll
    for (int j = 0; j < 4; j++){
      int cg = tx*4 + j;
      int q = cg >> 4, p = cg & 15;
      int nb = ids[p*20 + s*4 + q];
      float4 pvv = *(const float4*)&Pt[nb*64 + ty*4];
      float4 qvv = *(const float4*)&Qs[p*64 + ty*4];
      s16x4 gv;
      gv[0] = f2bs(lrelu((pvv.x+qvv.x - nm1[ty*4+0]) * niv1[ty*4+0]));
      gv[1] = f2bs(lrelu((pvv.y+qvv.y - nm1[ty*4+1]) * niv1[ty*4+1]));
      gv[2] = f2bs(lrelu((pvv.z+qvv.z - nm1[ty*4+2]) * niv1[ty*4+2]));
      gv[3] = f2bs(lrelu((pvv.w+qvv.w - nm1[ty*4+3]) * niv1[ty*4+3]));
      *(s16x4*)&Gs[cg][ty*4] = gv;
    }
    __syncthreads();
    #pragma unroll
    for (int q = 0; q < 4; q++){
      bfrag b0 = *(bfrag*)&Gs[q*16 + nn][quad*8];
      bfrag b1 = *(bfrag*)&Gs[q*16 + nn][32 + quad*8];
      f32x4 acc = {0.f, 0.f, 0.f, 0.f};
      acc = mfma16(af0, b0, acc);
      acc = mfma16(af1, b1, acc);
      #pragma unroll
      for (int r = 0; r < 4; r++){
        float v = acc[r];
        sacc[r] += v; qacc[r] += v*v;
        mxr[r] = fmaxf(mxr[r], v);
      }
    }
    __syncthreads();
  }

  #pragma unroll
  for (int r = 0; r < 4; r++){
    int rr = 16*w + quad*4 + r;
    float s = sacc[r], q2 = qacc[r];
    #pragma unroll
    for (int off = 8; off; off >>= 1){
      s  += __shfl_down(s, off, 16);
      q2 += __shfl_down(q2, off, 16);
    }
    if (nn == 0){
      atomicAdd(&stats2[rr], s);
      atomicAdd(&stats2[256+rr], q2);
    }
    rawmax[rr*NPTS + n0 + nn] = mxr[r];
  }
}

// ---------------------------------------------------------------- W9 GEMM (K=256) with fused maxres->x4
__global__ __launch_bounds__(256) void gemm9_kernel(
    const void* __restrict__ W,
    const float* __restrict__ xs,
    const float* __restrict__ rmaxp, const float* __restrict__ st2raw,
    const float* __restrict__ x3, float* __restrict__ x4,
    float* __restrict__ stats, unsigned* __restrict__ maxenc,
    const int* __restrict__ flagp)
{
  __shared__ __align__(16) short Fs[64][72];
  __shared__ float nm2[64], niv2[64];
  const int t = threadIdx.x;
  const int isbf = (*flagp == 0);
  const int colbase = (blockIdx.x & 127) * 64;
  const int rb = (blockIdx.x >> 7) * 64;
  const int lane = t & 63, w = t >> 6;
  const int nn = lane & 15, quad = lane >> 4;

  if (t < 64){
    const float invMB = 1.0f/(float)MBIG;
    float m = st2raw[t] * invMB;
    float v = st2raw[256+t]*invMB - m*m;
    nm2[t] = m;
    niv2[t] = 1.0f / sqrtf(fmaxf(v, 0.f) + EPSN);
  }

  bfrag af[8];
  const int arow = rb + 16*w + nn;
  #pragma unroll
  for (int f = 0; f < 8; f++)
    #pragma unroll
    for (int j = 0; j < 8; j++)
      af[f][j] = f2bs(ldx(W, arow*256 + f*32 + quad*8 + j, isbf));

  f32x4 acc[4] = {};
  const int jcol = t & 63, kg = t >> 6;

  for (int kc = 0; kc < 256; kc += 64){
    __syncthreads();
    #pragma unroll
    for (int u = 0; u < 4; u++){
      int kl = kg*16 + u*4;
      s16x4 pk;
      #pragma unroll
      for (int z = 0; z < 4; z++){
        int k = kc + kl + z;
        float v;
        if (k < 192){
          v = xs[k*NPTS + colbase + jcol];
        } else {
          int kk = k - 192;
          float rv = rmaxp[kk*NPTS + colbase + jcol];
          v = lrelu((rv - nm2[kk]) * niv2[kk]) + x3[kk*NPTS + colbase + jcol];
          if (rb == 0) x4[kk*NPTS + colbase + jcol] = v;
        }
        pk[z] = f2bs(v);
      }
      *(s16x4*)&Fs[jcol][kl] = pk;
    }
    __syncthreads();
    const int f0 = kc >> 5;
    #pragma unroll
    for (int q = 0; q < 4; q++){
      bfrag b0 = *(bfrag*)&Fs[q*16+nn][quad*8];
      bfrag b1 = *(bfrag*)&Fs[q*16+nn][32 + quad*8];
      acc[q] = mfma16(af[f0],   b0, acc[q]);
      acc[q] = mfma16(af[f0+1], b1, acc[q]);
    }
  }

  #pragma unroll
  for (int r = 0; r < 4; r++){
    int rr = rb + 16*w + quad*4 + r;
    float sum = 0.f, q2 = 0.f, mxv = -3.4e38f;
    #pragma unroll
    for (int q = 0; q < 4; q++){
      float v = acc[q][r];
      sum += v; q2 += v*v; mxv = fmaxf(mxv, v);
    }
    #pragma unroll
    for (int off = 8; off; off >>= 1){
      sum += __shfl_down(sum, off, 16);
      q2  += __shfl_down(q2, off, 16);
      mxv  = fmaxf(mxv, __shfl_down(mxv, off, 16));
    }
    if (nn == 0){
      atomicAdd(&stats[rr], sum);
      atomicAdd(&stats[256+rr], q2);
      atomicMax(&maxenc[rr], fenc(mxv));
    }
  }
}

// ---------------------------------------------------------------- W10 GEMM (K=64) with fused finalize_g
__global__ __launch_bounds__(256) void gemm10_kernel(
    const void* __restrict__ W,
    const float* __restrict__ B,            // x4
    const float* __restrict__ statsG, const unsigned* __restrict__ gmaxenc,
    float* __restrict__ Y,
    float* __restrict__ stats,
    const int* __restrict__ flagp)
{
  __shared__ __align__(16) short Fs[64][72];
  __shared__ float gsh[128], c0s[64];
  const int t = threadIdx.x;
  const int isbf = (*flagp == 0);
  const int colbase = (blockIdx.x & 127) * 64;
  const int rb = (blockIdx.x >> 7) * 64;
  const int lane = t & 63, w = t >> 6;
  const int nn = lane & 15, quad = lane >> 4;
  const float invMN = 1.0f/(float)NPTS;

  if (t < 128){
    float m = statsG[t] * invMN;
    float v = statsG[256+t]*invMN - m*m;
    float iv = 1.0f / sqrtf(fmaxf(v, 0.f) + EPSN);
    gsh[t] = lrelu((fdec(gmaxenc[t]) - m) * iv);
  }
  __syncthreads();
  if (t < 64){
    float s = 0.f;
    for (int j = 0; j < 128; j++) s += ldx(W, (rb + t)*192 + j, isbf) * gsh[j];
    c0s[t] = s;
  }

  bfrag af[2];
  const int arow = rb + 16*w + nn;
  #pragma unroll
  for (int f = 0; f < 2; f++)
    #pragma unroll
    for (int j = 0; j < 8; j++)
      af[f][j] = f2bs(ldx(W, arow*192 + 128 + f*32 + quad*8 + j, isbf));

  f32x4 acc[4] = {};
  const int jcol = t & 63, kg = t >> 6;

  {
    __syncthreads();
    #pragma unroll
    for (int u = 0; u < 4; u++){
      int kl = kg*16 + u*4;
      s16x4 pk;
      #pragma unroll
      for (int z = 0; z < 4; z++){
        int k = kl + z;
        pk[z] = f2bs(B[k*NPTS + colbase + jcol]);
      }
      *(s16x4*)&Fs[jcol][kl] = pk;
    }
    __syncthreads();
    #pragma unroll
    for (int q = 0; q < 4; q++){
      bfrag b0 = *(bfrag*)&Fs[q*16+nn][quad*8];
      bfrag b1 = *(bfrag*)&Fs[q*16+nn][32 + quad*8];
      acc[q] = mfma16(af[0], b0, acc[q]);
      acc[q] = mfma16(af[1], b1, acc[q]);
    }
  }

  #pragma unroll
  for (int r = 0; r < 4; r++){
    int rl = 16*w + quad*4 + r;
    int rr = rb + rl;
    float cv = c0s[rl];
    float sum = 0.f, q2 = 0.f;
    #pragma unroll
    for (int q = 0; q < 4; q++){
      float v = acc[q][r] + cv;
      sum += v; q2 += v*v;
      Y[rr*NPTS + colbase + q*16 + nn] = v;
    }
    #pragma unroll
    for (int off = 8; off; off >>= 1){
      sum += __shfl_down(sum, off, 16);
      q2  += __shfl_down(q2, off, 16);
    }
    if (nn == 0){
      atomicAdd(&stats[rr], sum);
      atomicAdd(&stats[256+rr], q2);
    }
  }
}

// ---------------------------------------------------------------- 1d GEMMs (MFMA)
template<int CTOT>
__global__ __launch_bounds__(256) void gemm1d_kernel(
    const void* __restrict__ W, int ldw, int koffW,
    const float* __restrict__ A, const float* __restrict__ Araw, float invA, int CA,
    const float* __restrict__ B,
    const float* __restrict__ cvec,
    float* __restrict__ Y,
    float* __restrict__ stats, unsigned* __restrict__ maxenc,
    const int* __restrict__ flagp)
{
  __shared__ __align__(16) short Fs[64][72];
  __shared__ float am[256], aiv[256];
  const int t = threadIdx.x;
  const int isbf = (*flagp == 0);
  const int colbase = (blockIdx.x & 127) * 64;
  const int rb = (blockIdx.x >> 7) * 64;
  const int lane = t & 63, w = t >> 6;
  const int nn = lane & 15, quad = lane >> 4;

  if (Araw && t < CA){
    float m = Araw[t]*invA;
    float v = Araw[256+t]*invA - m*m;
    am[t] = m; aiv[t] = 1.0f/sqrtf(fmaxf(v,0.f)+EPSN);
  }

  constexpr int K32 = CTOT >> 5;
  bfrag af[K32];
  const int arow = rb + 16*w + nn;
  #pragma unroll
  for (int f = 0; f < K32; f++)
    #pragma unroll
    for (int j = 0; j < 8; j++)
      af[f][j] = f2bs(ldx(W, arow*ldw + koffW + f*32 + quad*8 + j, isbf));

  f32x4 acc[4] = {};
  const int jcol = t & 63, kg = t >> 6;

  for (int kc = 0; kc < CTOT; kc += 64){
    __syncthreads();
    #pragma unroll
    for (int u = 0; u < 4; u++){
      int kl = kg*16 + u*4;
      s16x4 pk;
      #pragma unroll
      for (int z = 0; z < 4; z++){
        int k = kc + kl + z;
        float v;
        if (k < CA){
          v = A[k*NPTS + colbase + jcol];
          if (Araw) v = lrelu((v - am[k]) * aiv[k]);
        } else {
          v = B[(k-CA)*NPTS + colbase + jcol];
        }
        pk[z] = f2bs(v);
      }
      *(s16x4*)&Fs[jcol][kl] = pk;
    }
    __syncthreads();
    const int f0 = kc >> 5;
    #pragma unroll
    for (int q = 0; q < 4; q++){
      bfrag b0 = *(bfrag*)&Fs[q*16+nn][quad*8];
      bfrag b1 = *(bfrag*)&Fs[q*16+nn][32 + quad*8];
      acc[q] = mfma16(af[f0],   b0, acc[q]);
      acc[q] = mfma16(af[f0+1], b1, acc[q]);
    }
  }

  #pragma unroll
  for (int r = 0; r < 4; r++){
    int rr = rb + 16*w + quad*4 + r;
    float cv = cvec ? cvec[rr] : 0.f;
    float sum = 0.f, q2 = 0.f, mxv = -3.4e38f;
    #pragma unroll
    for (int q = 0; q < 4; q++){
      float v = acc[q][r] + cv;
      sum += v; q2 += v*v; mxv = fmaxf(mxv, v);
      if (Y) Y[rr*NPTS + colbase + q*16 + nn] = v;
    }
    #pragma unroll
    for (int off = 8; off; off >>= 1){
      sum += __shfl_down(sum, off, 16);
      q2  += __shfl_down(q2, off, 16);
      mxv  = fmaxf(mxv, __shfl_down(mxv, off, 16));
    }
    if (nn == 0){
      atomicAdd(&stats[rr], sum);
      atomicAdd(&stats[256+rr], q2);
      if (maxenc) atomicMax(&maxenc[rr], fenc(mxv));
    }
  }
}

// ---------------------------------------------------------------- segment sum
__global__ __launch_bounds__(256) void segsum_kernel(
    const float* __restrict__ ybuf, const float* __restrict__ straw,
    const int* __restrict__ tag, float* __restrict__ seg, float* __restrict__ cnt)
{
  const float invMN = 1.0f/(float)NPTS;
  int g = blockIdx.x*256 + threadIdx.x;
  int c = g >> 13, n = g & (NPTS-1);
  float m = straw[c] * invMN;
  float vv = straw[256+c]*invMN - m*m;
  float iv = 1.0f / sqrtf(fmaxf(vv, 0.f) + EPSN);
  float v = lrelu((ybuf[c*NPTS + n] - m) * iv);
  int tg = tag[n] & 7;
  int lane = threadIdx.x & 63;
  int t0 = __shfl(tg, 0, 64);
  bool uni = __all(tg == t0);
  if (uni){
    #pragma unroll
    for (int off = 32; off; off >>= 1) v += __shfl_down(v, off, 64);
    if (lane == 0){
      atomicAdd(&seg[t0*64 + c], v);
      if (c == 0) atomicAdd(cnt + t0, 64.f);
    }
  } else {
    atomicAdd(&seg[tg*64 + c], v);
    if (c == 0) atomicAdd(cnt + tg, 1.f);
  }
}

// ---------------------------------------------------------------- final out
__global__ void final_kernel(const void* __restrict__ Wr,
    const float* __restrict__ seg, const float* __restrict__ cnt,
    void* __restrict__ out, int total, const int* __restrict__ flagp)
{
  const int isbf = (*flagp == 0);
  int q = blockIdx.x*blockDim.x + threadIdx.x;
  if (q >= total) return;
  int g = q >> 7, c = q & 127;
  float s = 0.f;
  for (int j = 0; j < 64; j++) s += ldx(Wr, c*64 + j, isbf) * seg[g*64 + j];
  float r = s / fmaxf(cnt[g], 1.f);
  if (isbf) ((bf16*)out)[q] = __float2bfloat16(r);
  else      ((float*)out)[q] = r;
}

// ================================================================ host
extern "C" void kernel_launch(void* const* d_in, const int* in_sizes, int n_in,
                              void* d_out, int out_size, void* d_ws, size_t ws_size,
                              hipStream_t stream)
{
  const void* x   = d_in[0];
  const int* tag  = (const int*)d_in[1];
  const void* W1  = d_in[3];
  const void* W2  = d_in[4];
  const void* W3  = d_in[5];
  const void* W4  = d_in[6];
  const void* W5  = d_in[7];
  const void* W6  = d_in[8];
  const void* W7  = d_in[9];
  const void* W8  = d_in[10];
  const void* W9  = d_in[11];
  const void* W10 = d_in[12];
  const void* W11 = d_in[13];
  const void* W12 = d_in[14];
  const void* W13 = d_in[15];
  const void* Wr  = d_in[16];

  char* ws = (char*)d_ws;
  int*      idxc = (int*)ws;                        // 8192*80*4   = 2,621,440
  float*    xs   = (float*)(ws + 2621440);          // 4*64*8192*4 = 8,388,608
  float* x1 = xs;
  float* x2 = xs +  64*NPTS;
  float* x3 = xs + 128*NPTS;
  float* x4 = xs + 192*NPTS;
  float*    y0   = (float*)(ws + 11010048);         // 128*8192*4 = 4,194,304
  float*    y1   = (float*)(ws + 15204352);         // 4,194,304
  float*    rmax = (float*)(ws + 19398656);         // 64*8192*4  = 2,097,152
  float*    Pt   = y0;                              // alias: P/Q dead before decoder
  float*    Qt   = y0 + 64*NPTS;
  float*    st   = (float*)(ws + 21495808);         // 16384 floats (64 KB)
  auto L = [&](int l){ return st + l*1024; };       // raw sum|sumsq x256 each
  int*      flag     = (int*)(st + 13312);          // badf: 0 => bf16
  unsigned* gmaxenc  = (unsigned*)(st + 13440);
  float*    seg      = st + 13824;
  float*    cnt      = seg + 512;

  zero_kernel<<<64, 256, 0, stream>>>(st, 16384);
  detect_kernel<<<12, 256, 0, stream>>>(x, flag);
  knn_kernel<<<2048, 256, 0, stream>>>(x, tag, idxc, flag);

  // stage 1
  pq3_kernel<<<128, 256, 0, stream>>>(x, W1, Pt, Qt, flag);
  stats1_kernel<<<512, 256, 0, stream>>>(Pt, Qt, idxc, 0, L(0));
  conv2_kernel<<<512, 256, 0, stream>>>(Pt, Qt, idxc, 0, W2, L(0), L(1), rmax, flag);
  // stage 2 (pqm fuses maxres of stage 1 -> x1)
  pqm_kernel<<<256, 256, 0, stream>>>(rmax, W3, L(1), nullptr, Pt, Qt, x1, flag);
  stats1_kernel<<<512, 256, 0, stream>>>(Pt, Qt, idxc, 1, L(2));
  conv2_kernel<<<512, 256, 0, stream>>>(Pt, Qt, idxc, 1, W4, L(2), L(3), rmax, flag);
  // stage 3 (fused maxres of stage 2 -> x2, resid x1)
  pqm_kernel<<<256, 256, 0, stream>>>(rmax, W5, L(3), x1, Pt, Qt, x2, flag);
  stats1_kernel<<<512, 256, 0, stream>>>(Pt, Qt, idxc, 2, L(4));
  conv2_kernel<<<512, 256, 0, stream>>>(Pt, Qt, idxc, 2, W6, L(4), L(5), rmax, flag);
  // stage 4 (fused maxres of stage 3 -> x3, resid x2)
  pqm_kernel<<<256, 256, 0, stream>>>(rmax, W7, L(5), x2, Pt, Qt, x3, flag);
  stats1_kernel<<<512, 256, 0, stream>>>(Pt, Qt, idxc, 3, L(6));
  conv2_kernel<<<512, 256, 0, stream>>>(Pt, Qt, idxc, 3, W8, L(6), L(7), rmax, flag);

  // ---- g: W9 GEMM with fused maxres (x4 materialized as byproduct)
  gemm9_kernel<<<256, 256, 0, stream>>>(W9, xs, rmax, L(7), x3, x4,
                                        L(8), gmaxenc, flag);

  const float invMN = 1.0f/(float)NPTS;
  // ---- decoder chain (W10 fuses finalize_g)
  gemm10_kernel<<<256, 256, 0, stream>>>(W10, x4, L(8), gmaxenc, y0, L(9), flag);
  gemm1d_kernel<192><<<256, 256, 0, stream>>>(W11, 192, 0, y0, L(9), invMN, 128,
                                              x3, nullptr, y1, L(10), nullptr, flag);
  gemm1d_kernel<192><<<128, 256, 0, stream>>>(W12, 192, 0, y1, L(10), invMN, 128,
                                              x2, nullptr, y0, L(11), nullptr, flag);
  gemm1d_kernel<128><<<128, 256, 0, stream>>>(W13, 128, 0, y0, L(11), invMN, 64,
                                              x1, nullptr, y1, L(12), nullptr, flag);

  // ---- code pooling: segment-sum commutes with Wr
  segsum_kernel<<<64*NPTS/256, 256, 0, stream>>>(y1, L(12), tag, seg, cnt);
  final_kernel<<<4, 256, 0, stream>>>(Wr, seg, cnt, d_out, out_size, flag);
}